// Round 1
// baseline (1454.417 us; speedup 1.0000x reference)
//
#include <hip/hip_runtime.h>
#include <math.h>

#define NPTS 131072

struct Planes9 { const float* p[9]; };

__device__ __forceinline__ float sp100(float h) {
    float z = 100.0f * h;
    return (fmaxf(z, 0.0f) + log1pf(__expf(-fabsf(z)))) * 0.01f;
}

__host__ __device__ constexpr size_t plane_off(int pl) {
    size_t o = 0;
    for (int i = 0; i < pl; ++i) o += (size_t)262144 << (2 * (i % 3));
    return o;
}

// ---------------- gather: one plane chunk (64 ch) for 64 points -> lds featT[c][pt], stride 65
template<int PL, bool TR>
__device__ __forceinline__ void gather_plane(const float* __restrict__ plane,
                                             const float* __restrict__ xs,
                                             float* __restrict__ feat,
                                             int gp, int gc)
{
    constexpr int G = PL / 3, R = PL % 3, L = 64 << R;
    float u, v;
    if constexpr (G == 0)      { u = xs[gp*3+0]; v = xs[gp*3+1]; }   // xy
    else if constexpr (G == 1) { u = xs[gp*3+0]; v = xs[gp*3+2]; }   // xz
    else                       { u = xs[gp*3+1]; v = xs[gp*3+2]; }   // yz
    float ix = (u + 1.0f) * 0.5f * (float)(L - 1);
    float iy = (v + 1.0f) * 0.5f * (float)(L - 1);
    float ix0 = floorf(ix), iy0 = floorf(iy);
    float wx = ix - ix0, wy = iy - iy0;
    int x0 = (int)fminf(fmaxf(ix0, 0.0f), (float)(L - 1));
    int x1 = (int)fminf(fmaxf(ix0 + 1.0f, 0.0f), (float)(L - 1));
    int y0 = (int)fminf(fmaxf(iy0, 0.0f), (float)(L - 1));
    int y1 = (int)fminf(fmaxf(iy0 + 1.0f, 0.0f), (float)(L - 1));
    float wnw = (1.0f - wx) * (1.0f - wy);
    float wne = wx * (1.0f - wy);
    float wsw = (1.0f - wx) * wy;
    float wse = wx * wy;
    if constexpr (TR) {
        // transposed (H,W,C) layout: 64 contiguous channels per corner
        const float4* c00 = (const float4*)(plane + ((y0 * L + x0) * 64 + gc * 16));
        const float4* c01 = (const float4*)(plane + ((y0 * L + x1) * 64 + gc * 16));
        const float4* c10 = (const float4*)(plane + ((y1 * L + x0) * 64 + gc * 16));
        const float4* c11 = (const float4*)(plane + ((y1 * L + x1) * 64 + gc * 16));
        #pragma unroll
        for (int q = 0; q < 4; ++q) {
            float4 a = c00[q], b = c01[q], c = c10[q], d = c11[q];
            int cb = gc * 16 + q * 4;
            feat[(cb+0)*65 + gp] = wnw*a.x + wne*b.x + wsw*c.x + wse*d.x;
            feat[(cb+1)*65 + gp] = wnw*a.y + wne*b.y + wsw*c.y + wse*d.y;
            feat[(cb+2)*65 + gp] = wnw*a.z + wne*b.z + wsw*c.z + wse*d.z;
            feat[(cb+3)*65 + gp] = wnw*a.w + wne*b.w + wsw*c.w + wse*d.w;
        }
    } else {
        // fallback: original (C,H,W) layout
        const int i00 = y0*L + x0, i01 = y0*L + x1, i10 = y1*L + x0, i11 = y1*L + x1;
        #pragma unroll 4
        for (int cc = 0; cc < 16; ++cc) {
            int ch = gc * 16 + cc;
            const float* pc = plane + (size_t)ch * (L * L);
            feat[ch*65 + gp] = wnw*pc[i00] + wne*pc[i01] + wsw*pc[i10] + wse*pc[i11];
        }
    }
}

// ---------------- GEMM piece: lane = point, 32 output columns, W at wave-uniform address
template<int KN>
__device__ __forceinline__ void gemm_half(const float* __restrict__ W,   // uniform base, row stride 256
                                          const float* __restrict__ A,   // lds featT, stride 65
                                          int lane, float* __restrict__ acc)
{
    #pragma unroll 2
    for (int k = 0; k < KN; ++k) {
        float a = A[k * 65 + lane];
        #pragma unroll
        for (int u = 0; u < 32; ++u)
            acc[u] = fmaf(a, W[k * 256 + u], acc[u]);
    }
}

// ---------------- fused kernel: 64 points / block, 256 threads
__global__ __launch_bounds__(256) void fused_kernel(
    const float* __restrict__ x, Planes9 pls, const float* __restrict__ tpl, int use_t,
    const float* __restrict__ W1t, const float* __restrict__ W2t, const float* __restrict__ Wlt,
    const float* __restrict__ b1, const float* __restrict__ b2, const float* __restrict__ bl,
    float* __restrict__ out)
{
    __shared__ float lds[128 * 65];
    __shared__ float xs[192];
    const int t = threadIdx.x;
    const int blk = blockIdx.x;
    if (t < 192) xs[t] = x[(size_t)blk * 192 + t];
    const int w = t >> 6, lane = t & 63;
    const int gp = t >> 2, gc = t & 3;
    const int obase = __builtin_amdgcn_readfirstlane(w << 6);  // wave-uniform output base

    float acc[64];
    #pragma unroll
    for (int u = 0; u < 64; ++u) acc[u] = 0.0f;
    __syncthreads();

    // ---- layer 1: loop 9 plane chunks (K = 9 * 64 = 576)
    #pragma unroll 1
    for (int pl = 0; pl < 9; ++pl) {
#define GCASE(PLI) case PLI: \
        if (use_t) gather_plane<PLI, true>(tpl + plane_off(PLI), xs, lds, gp, gc); \
        else       gather_plane<PLI, false>(pls.p[PLI], xs, lds, gp, gc); break;
        switch (pl) { GCASE(0) GCASE(1) GCASE(2) GCASE(3) GCASE(4) GCASE(5) GCASE(6) GCASE(7) GCASE(8) }
#undef GCASE
        __syncthreads();
        const float* Wu = W1t + (size_t)(pl * 64) * 256 + obase;
        gemm_half<64>(Wu,      lds, lane, acc);
        gemm_half<64>(Wu + 32, lds, lane, acc + 32);
        __syncthreads();
    }

    // softplus + bias -> h1 (wave w holds outs [obase, obase+64) for its 64 lane-points)
    float h[64];
    #pragma unroll
    for (int u = 0; u < 64; ++u) h[u] = sp100(acc[u] + b1[obase + u]);

    // ---- layer 2 (K = 256 in 2 chunks of 128 staged rows)
    #pragma unroll
    for (int u = 0; u < 64; ++u) acc[u] = 0.0f;
    #pragma unroll 1
    for (int c2 = 0; c2 < 2; ++c2) {
        if ((w >> 1) == c2) {
            #pragma unroll
            for (int u = 0; u < 64; ++u)
                lds[(((w & 1) << 6) + u) * 65 + lane] = h[u];
        }
        __syncthreads();
        const float* Wu = W2t + (size_t)(c2 * 128) * 256 + obase;
        gemm_half<128>(Wu,      lds, lane, acc);
        gemm_half<128>(Wu + 32, lds, lane, acc + 32);
        __syncthreads();
    }
    #pragma unroll
    for (int u = 0; u < 64; ++u) h[u] = sp100(acc[u] + b2[obase + u]);

    // ---- layer 3 (65 outs; wave w covers outs [w*16, w*16+16), wave 3 also out 64)
    float acc3[17];
    #pragma unroll
    for (int j = 0; j < 17; ++j) acc3[j] = 0.0f;
    const int o3 = obase >> 2;            // w * 16, uniform
    const bool last = (w == 3);
    #pragma unroll 1
    for (int c2 = 0; c2 < 2; ++c2) {
        if ((w >> 1) == c2) {
            #pragma unroll
            for (int u = 0; u < 64; ++u)
                lds[(((w & 1) << 6) + u) * 65 + lane] = h[u];
        }
        __syncthreads();
        const float* Wl = Wlt + (size_t)(c2 * 128) * 65 + o3;
        #pragma unroll 2
        for (int k = 0; k < 128; ++k) {
            float a = lds[k * 65 + lane];
            #pragma unroll
            for (int j = 0; j < 16; ++j)
                acc3[j] = fmaf(a, Wl[k * 65 + j], acc3[j]);
            if (last) acc3[16] = fmaf(a, Wl[k * 65 + 16], acc3[16]);
        }
        __syncthreads();
    }

    // stage outputs (+ bias) in LDS, then coalesced write
    #pragma unroll
    for (int j = 0; j < 16; ++j)
        lds[(o3 + j) * 65 + lane] = acc3[j] + bl[o3 + j];
    if (last) lds[64 * 65 + lane] = acc3[16] + bl[64];
    __syncthreads();
    #pragma unroll
    for (int rep = 0; rep < 16; ++rep) {
        int idx = rep * 256 + t;
        int pp = idx >> 6, oo = idx & 63;
        out[((size_t)blk * 64 + pp) * 64 + oo] = lds[oo * 65 + pp];
    }
    if (t < 64) out[(size_t)NPTS * 64 + (size_t)blk * 64 + t] = lds[64 * 65 + t];
}

// ---------------- weight-norm + transpose to k-major
__global__ __launch_bounds__(64) void prep_weights(
    const float* __restrict__ v1, const float* __restrict__ g1,
    const float* __restrict__ v2, const float* __restrict__ g2,
    const float* __restrict__ vl, const float* __restrict__ gl,
    float* __restrict__ W1t, float* __restrict__ W2t, float* __restrict__ Wlt)
{
    int i = blockIdx.x, t = threadIdx.x;
    const float* src; float g; int K;
    if (i < 256)      { src = v1 + (size_t)i * 576;        g = g1[i];       K = 576; }
    else if (i < 512) { src = v2 + (size_t)(i-256) * 256;  g = g2[i-256];   K = 256; }
    else              { src = vl + (size_t)(i-512) * 256;  g = gl[i-512];   K = 256; }
    float s = 0.0f;
    for (int k = t; k < K; k += 64) { float wv = src[k]; s += wv * wv; }
    #pragma unroll
    for (int off = 32; off > 0; off >>= 1) s += __shfl_xor(s, off, 64);
    float sc = g / sqrtf(s);
    if (i < 256)      { for (int k = t; k < 576; k += 64) W1t[k*256 + i]       = src[k] * sc; }
    else if (i < 512) { for (int k = t; k < 256; k += 64) W2t[k*256 + (i-256)] = src[k] * sc; }
    else              { for (int k = t; k < 256; k += 64) Wlt[k*65  + (i-512)] = src[k] * sc; }
}

// ---------------- planes (C,H,W) -> (H,W,C)
__global__ __launch_bounds__(256) void transpose_planes(Planes9 pls, float* __restrict__ dst)
{
    __shared__ float tile[64 * 65];
    int b = blockIdx.x;                 // 0..4031
    int g = b / 1344, rem = b % 1344;
    int r, t2;
    if (rem < 64)       { r = 0; t2 = rem; }
    else if (rem < 320) { r = 1; t2 = rem - 64; }
    else                { r = 2; t2 = rem - 320; }
    int L = 64 << r;
    int wt = L >> 6;
    int y = t2 / wt, xt = t2 % wt;
    const float* sp = pls.p[g * 3 + r];
    float* dp = dst + (size_t)g * 5505024 + (r == 0 ? 0 : (r == 1 ? 262144 : 1310720));
    int t = threadIdx.x;
    int rowbase = y * L + xt * 64;
    {
        int xi = t & 63, cq = t >> 6;
        #pragma unroll
        for (int cc = 0; cc < 16; ++cc) {
            int c = cq * 16 + cc;
            tile[c * 65 + xi] = sp[(size_t)c * L * L + rowbase + xi];
        }
    }
    __syncthreads();
    {
        int ci = t & 63, xq = t >> 6;
        #pragma unroll
        for (int xx = 0; xx < 16; ++xx) {
            int xcol = xq * 16 + xx;
            dp[(size_t)(rowbase + xcol) * 64 + ci] = tile[ci * 65 + xcol];
        }
    }
}

extern "C" void kernel_launch(void* const* d_in, const int* in_sizes, int n_in,
                              void* d_out, int out_size, void* d_ws, size_t ws_size,
                              hipStream_t stream)
{
    const float* x = (const float*)d_in[0];
    Planes9 pls;
    for (int i = 0; i < 9; ++i) pls.p[i] = (const float*)d_in[1 + i];
    const float* v1 = (const float*)d_in[10];
    const float* g1 = (const float*)d_in[11];
    const float* b1 = (const float*)d_in[12];
    const float* v2 = (const float*)d_in[13];
    const float* g2 = (const float*)d_in[14];
    const float* b2 = (const float*)d_in[15];
    const float* vl = (const float*)d_in[16];
    const float* gl = (const float*)d_in[17];
    const float* bl = (const float*)d_in[18];

    float* ws  = (float*)d_ws;
    float* W1t = ws;                  // 576*256 = 147456
    float* W2t = ws + 147456;         // 256*256 =  65536
    float* Wlt = ws + 212992;         // 256*65  =  16640
    float* tpl = ws + 262144;         // transposed planes: 16515072 floats
    const int use_t = (ws_size >= (size_t)(262144 + 16515072) * sizeof(float)) ? 1 : 0;

    prep_weights<<<577, 64, 0, stream>>>(v1, g1, v2, g2, vl, gl, W1t, W2t, Wlt);
    if (use_t) transpose_planes<<<4032, 256, 0, stream>>>(pls, tpl);
    fused_kernel<<<NPTS / 64, 256, 0, stream>>>(x, pls, tpl, use_t,
                                                W1t, W2t, Wlt, b1, b2, bl,
                                                (float*)d_out);
}

// Round 2
// 923.835 us; speedup vs baseline: 1.5743x; 1.5743x over previous
//
#include <hip/hip_runtime.h>
#include <math.h>

#define NPTS 131072

typedef short s16x8 __attribute__((ext_vector_type(8)));
typedef short s16x4 __attribute__((ext_vector_type(4)));
typedef float f32x4 __attribute__((ext_vector_type(4)));

struct Planes9 { const float* p[9]; };

__device__ __forceinline__ float sp100(float h) {
    float z = 100.0f * h;
    return (fmaxf(z, 0.0f) + log1pf(__expf(-fabsf(z)))) * 0.01f;
}

__device__ __forceinline__ short f2bf(float f) {
    union { float f; unsigned u; } a; a.f = f;
    unsigned u = a.u;
    return (short)((u + 0x7FFFu + ((u >> 16) & 1u)) >> 16);
}
__device__ __forceinline__ float bf2f(short h) {
    union { unsigned u; float f; } a; a.u = ((unsigned)(unsigned short)h) << 16;
    return a.f;
}

__device__ __forceinline__ f32x4 mm(s16x8 a, s16x8 b, f32x4 c) {
    return __builtin_amdgcn_mfma_f32_16x16x32_bf16(a, b, c, 0, 0, 0);
}

// ================= fused kernel: 128 points / block, 256 threads (4 waves) ==============
// D[n][m] = W * feat^T form. Waves split N into interleaved 16-tiles T = 4j + w.
__global__ __launch_bounds__(256, 2) void fused_kernel(
    const float* __restrict__ x, Planes9 pls, const float* __restrict__ tpl, int use_t,
    const short* __restrict__ W1h, const short* __restrict__ W1l,
    const short* __restrict__ W2h, const short* __restrict__ W2l,
    const short* __restrict__ Wlh, const short* __restrict__ Wll,
    const float* __restrict__ b1, const float* __restrict__ b2, const float* __restrict__ bl,
    float* __restrict__ out)
{
    __shared__ __align__(16) char smem[65536];   // feat chunk (hi@0 16K, lo@16K) aliased under hB[128][256] bf16
    __shared__ float xs[384];
    const int t = threadIdx.x, blk = blockIdx.x;
    for (int i = t; i < 384; i += 256) xs[i] = x[(size_t)blk * 384 + i];

    const int w = t >> 6, ln = t & 63, s = ln & 15, g = ln >> 4;
    const int swz = (s & 7) << 4;
    const int pt = t & 127, kh = t >> 7;        // gather role: point, channel-half
    const int ptswz = (pt & 7) << 4;

    f32x4 acc[8][4];
    const f32x4 fz = {0.f, 0.f, 0.f, 0.f};
    #pragma unroll
    for (int mt = 0; mt < 8; ++mt)
        #pragma unroll
        for (int j = 0; j < 4; ++j) acc[mt][j] = fz;

    __syncthreads();

    // ================= Layer 1: loop 9 plane chunks (K = 576) =================
    #pragma unroll 1
    for (int pl = 0; pl < 9; ++pl) {
        const int grp = (pl >= 6) ? 2 : (pl >= 3 ? 1 : 0);
        const int r = pl - grp * 3;
        const int L = 64 << r;
        float u, v;
        { float xc0 = xs[pt*3+0], xc1 = xs[pt*3+1], xc2 = xs[pt*3+2];
          u = (grp == 2) ? xc1 : xc0;
          v = (grp == 0) ? xc1 : xc2; }
        float ix = (u + 1.0f) * 0.5f * (float)(L - 1);
        float iy = (v + 1.0f) * 0.5f * (float)(L - 1);
        float ix0 = floorf(ix), iy0 = floorf(iy);
        float wx = ix - ix0, wy = iy - iy0;
        int x0 = (int)fminf(fmaxf(ix0, 0.f), (float)(L-1));
        int x1 = (int)fminf(fmaxf(ix0+1.f, 0.f), (float)(L-1));
        int y0 = (int)fminf(fmaxf(iy0, 0.f), (float)(L-1));
        int y1 = (int)fminf(fmaxf(iy0+1.f, 0.f), (float)(L-1));
        float wnw = (1.f-wx)*(1.f-wy), wne = wx*(1.f-wy), wsw = (1.f-wx)*wy, wse = wx*wy;

        float f[32];
        if (use_t) {
            size_t poff = (size_t)grp * 5505024 + (r == 0 ? 0u : (r == 1 ? 262144u : 1310720u));
            const float* P = tpl + poff;
            const float4* c00 = (const float4*)(P + ((size_t)(y0*L + x0)*64 + kh*32));
            const float4* c01 = (const float4*)(P + ((size_t)(y0*L + x1)*64 + kh*32));
            const float4* c10 = (const float4*)(P + ((size_t)(y1*L + x0)*64 + kh*32));
            const float4* c11 = (const float4*)(P + ((size_t)(y1*L + x1)*64 + kh*32));
            #pragma unroll
            for (int q = 0; q < 8; ++q) {
                float4 a = c00[q], b = c01[q], c = c10[q], d = c11[q];
                f[q*4+0] = wnw*a.x + wne*b.x + wsw*c.x + wse*d.x;
                f[q*4+1] = wnw*a.y + wne*b.y + wsw*c.y + wse*d.y;
                f[q*4+2] = wnw*a.z + wne*b.z + wsw*c.z + wse*d.z;
                f[q*4+3] = wnw*a.w + wne*b.w + wsw*c.w + wse*d.w;
            }
        } else {
            const float* P = pls.p[pl];
            const int i00 = y0*L+x0, i01 = y0*L+x1, i10 = y1*L+x0, i11 = y1*L+x1;
            #pragma unroll 8
            for (int c = 0; c < 32; ++c) {
                const float* pc = P + (size_t)(kh*32 + c) * L * L;
                f[c] = wnw*pc[i00] + wne*pc[i01] + wsw*pc[i10] + wse*pc[i11];
            }
        }
        // split fp32 -> bf16 hi/lo, stage to LDS featB [128 m][64 k], XOR-swizzled 16B chunks
        #pragma unroll
        for (int q = 0; q < 4; ++q) {
            s16x8 hi8, lo8;
            #pragma unroll
            for (int e = 0; e < 8; ++e) {
                float vv = f[q*8+e];
                short hb = f2bf(vv);
                hi8[e] = hb;
                lo8[e] = f2bf(vv - bf2f(hb));
            }
            int off = pt*128 + ((kh*64 + q*16) ^ ptswz);
            *(s16x8*)(smem + off)         = hi8;
            *(s16x8*)(smem + 16384 + off) = lo8;
        }
        __syncthreads();

        // MFMA: 3-term split (Ah*Bh + Ah*Bl + Al*Bh)
        #pragma unroll
        for (int ks = 0; ks < 2; ++ks) {
            s16x8 Ah[4], Al[4];
            #pragma unroll
            for (int j = 0; j < 4; ++j) {
                size_t ro = (size_t)((4*j + w)*16 + s) * 576 + (size_t)(pl*64 + ks*32 + g*8);
                Ah[j] = *(const s16x8*)(W1h + ro);
                Al[j] = *(const s16x8*)(W1l + ro);
            }
            #pragma unroll
            for (int mt = 0; mt < 8; ++mt) {
                int off = (mt*16 + s)*128 + ((ks*64 + g*16) ^ swz);
                s16x8 Bh = *(s16x8*)(smem + off);
                s16x8 Bl = *(s16x8*)(smem + 16384 + off);
                #pragma unroll
                for (int j = 0; j < 4; ++j) {
                    acc[mt][j] = mm(Ah[j], Bh, acc[mt][j]);
                    acc[mt][j] = mm(Ah[j], Bl, acc[mt][j]);
                    acc[mt][j] = mm(Al[j], Bh, acc[mt][j]);
                }
            }
        }
        __syncthreads();
    }

    // ======== bias + softplus, stage h1 (bf16 hi) to hB [128 m][256 k] ========
    #pragma unroll
    for (int j = 0; j < 4; ++j) {
        f32x4 bv = *(const f32x4*)(b1 + (4*j + w)*16 + g*4);
        #pragma unroll
        for (int mt = 0; mt < 8; ++mt) {
            f32x4 a = acc[mt][j];
            s16x4 hq;
            hq[0] = f2bf(sp100(a[0] + bv[0]));
            hq[1] = f2bf(sp100(a[1] + bv[1]));
            hq[2] = f2bf(sp100(a[2] + bv[2]));
            hq[3] = f2bf(sp100(a[3] + bv[3]));
            int off = (mt*16 + s)*512 + ((((4*j + w)*32) + g*8) ^ swz);
            *(s16x4*)(smem + off) = hq;
        }
    }
    #pragma unroll
    for (int mt = 0; mt < 8; ++mt)
        #pragma unroll
        for (int j = 0; j < 4; ++j) acc[mt][j] = fz;
    __syncthreads();

    // ================= Layer 2: K = 256, weights split (2-term) =================
    #pragma unroll 1
    for (int ks = 0; ks < 8; ++ks) {
        s16x8 Ah[4], Al[4];
        #pragma unroll
        for (int j = 0; j < 4; ++j) {
            size_t ro = (size_t)((4*j + w)*16 + s) * 256 + (size_t)(ks*32 + g*8);
            Ah[j] = *(const s16x8*)(W2h + ro);
            Al[j] = *(const s16x8*)(W2l + ro);
        }
        #pragma unroll
        for (int mt = 0; mt < 8; ++mt) {
            int off = (mt*16 + s)*512 + ((ks*64 + g*16) ^ swz);
            s16x8 B = *(s16x8*)(smem + off);
            #pragma unroll
            for (int j = 0; j < 4; ++j) {
                acc[mt][j] = mm(Ah[j], B, acc[mt][j]);
                acc[mt][j] = mm(Al[j], B, acc[mt][j]);
            }
        }
    }
    __syncthreads();   // all hB reads done before overwrite with h2

    // ======== bias + softplus, stage h2 ========
    #pragma unroll
    for (int j = 0; j < 4; ++j) {
        f32x4 bv = *(const f32x4*)(b2 + (4*j + w)*16 + g*4);
        #pragma unroll
        for (int mt = 0; mt < 8; ++mt) {
            f32x4 a = acc[mt][j];
            s16x4 hq;
            hq[0] = f2bf(sp100(a[0] + bv[0]));
            hq[1] = f2bf(sp100(a[1] + bv[1]));
            hq[2] = f2bf(sp100(a[2] + bv[2]));
            hq[3] = f2bf(sp100(a[3] + bv[3]));
            int off = (mt*16 + s)*512 + ((((4*j + w)*32) + g*8) ^ swz);
            *(s16x4*)(smem + off) = hq;
        }
    }
    __syncthreads();

    // ================= Layer 3: Wl padded to 128 rows; wave w does tiles w and 4+w =====
    f32x4 acc3[8][2];
    #pragma unroll
    for (int mt = 0; mt < 8; ++mt) { acc3[mt][0] = fz; acc3[mt][1] = fz; }
    #pragma unroll 1
    for (int ks = 0; ks < 8; ++ks) {
        s16x8 Ah[2], Al[2];
        #pragma unroll
        for (int j = 0; j < 2; ++j) {
            size_t ro = (size_t)((4*j + w)*16 + s) * 256 + (size_t)(ks*32 + g*8);
            Ah[j] = *(const s16x8*)(Wlh + ro);
            Al[j] = *(const s16x8*)(Wll + ro);
        }
        #pragma unroll
        for (int mt = 0; mt < 8; ++mt) {
            int off = (mt*16 + s)*512 + ((ks*64 + g*16) ^ swz);
            s16x8 B = *(s16x8*)(smem + off);
            #pragma unroll
            for (int j = 0; j < 2; ++j) {
                acc3[mt][j] = mm(Ah[j], B, acc3[mt][j]);
                acc3[mt][j] = mm(Al[j], B, acc3[mt][j]);
            }
        }
    }

    // ================= output: feat (P,64) + dsdf (P,1) =================
    {
        f32x4 bv = *(const f32x4*)(bl + w*16 + g*4);
        #pragma unroll
        for (int mt = 0; mt < 8; ++mt) {
            size_t p = (size_t)blk*128 + (size_t)(mt*16 + s);
            f32x4 o = acc3[mt][0];
            o[0] += bv[0]; o[1] += bv[1]; o[2] += bv[2]; o[3] += bv[3];
            *(f32x4*)(out + p*64 + (size_t)(w*16 + g*4)) = o;
            if (w == 0 && g == 0)
                out[(size_t)NPTS*64 + p] = acc3[mt][1][0] + bl[64];
        }
    }
}

// ---------------- weight-norm + bf16 hi/lo split (row-major n x k, k contiguous) -------
__global__ __launch_bounds__(64) void prep_weights(
    const float* __restrict__ v1, const float* __restrict__ g1,
    const float* __restrict__ v2, const float* __restrict__ g2,
    const float* __restrict__ vl, const float* __restrict__ gl,
    short* __restrict__ W1h, short* __restrict__ W1l,
    short* __restrict__ W2h, short* __restrict__ W2l,
    short* __restrict__ Wlh, short* __restrict__ Wll)
{
    int i = blockIdx.x, t = threadIdx.x;
    const float* src; float gv; int K; short *dh, *dl; size_t ro;
    if (i < 256)      { src = v1 + (size_t)i*576; gv = g1[i]; K = 576; dh = W1h; dl = W1l; ro = (size_t)i*576; }
    else if (i < 512) { int rr = i-256; src = v2 + (size_t)rr*256; gv = g2[rr]; K = 256; dh = W2h; dl = W2l; ro = (size_t)rr*256; }
    else {
        int rr = i-512;  // 0..127, pad rows 65..127 with zeros
        K = 256; dh = Wlh; dl = Wll; ro = (size_t)rr*256;
        if (rr >= 65) {
            for (int k = t; k < 256; k += 64) { dh[ro+k] = 0; dl[ro+k] = 0; }
            return;
        }
        src = vl + (size_t)rr*256; gv = gl[rr];
    }
    float ssum = 0.f;
    for (int k = t; k < K; k += 64) { float wv = src[k]; ssum += wv*wv; }
    #pragma unroll
    for (int off = 32; off > 0; off >>= 1) ssum += __shfl_xor(ssum, off, 64);
    float sc = gv / sqrtf(ssum);
    for (int k = t; k < K; k += 64) {
        float wv = src[k] * sc;
        short hb = f2bf(wv);
        dh[ro + k] = hb;
        dl[ro + k] = f2bf(wv - bf2f(hb));
    }
}

// ---------------- planes (C,H,W) -> (H,W,C) fp32 ----------------
__global__ __launch_bounds__(256) void transpose_planes(Planes9 pls, float* __restrict__ dst)
{
    __shared__ float tile[64 * 65];
    int b = blockIdx.x;                 // 0..4031
    int g = b / 1344, rem = b % 1344;
    int r, t2;
    if (rem < 64)       { r = 0; t2 = rem; }
    else if (rem < 320) { r = 1; t2 = rem - 64; }
    else                { r = 2; t2 = rem - 320; }
    int L = 64 << r;
    int wt = L >> 6;
    int y = t2 / wt, xt = t2 % wt;
    const float* sp = pls.p[g * 3 + r];
    float* dp = dst + (size_t)g * 5505024 + (r == 0 ? 0 : (r == 1 ? 262144 : 1310720));
    int t = threadIdx.x;
    int rowbase = y * L + xt * 64;
    {
        int xi = t & 63, cq = t >> 6;
        #pragma unroll
        for (int cc = 0; cc < 16; ++cc) {
            int c = cq * 16 + cc;
            tile[c * 65 + xi] = sp[(size_t)c * L * L + rowbase + xi];
        }
    }
    __syncthreads();
    {
        int ci = t & 63, xq = t >> 6;
        #pragma unroll
        for (int xx = 0; xx < 16; ++xx) {
            int xcol = xq * 16 + xx;
            dp[(size_t)(rowbase + xcol) * 64 + ci] = tile[ci * 65 + xcol];
        }
    }
}

extern "C" void kernel_launch(void* const* d_in, const int* in_sizes, int n_in,
                              void* d_out, int out_size, void* d_ws, size_t ws_size,
                              hipStream_t stream)
{
    const float* x = (const float*)d_in[0];
    Planes9 pls;
    for (int i = 0; i < 9; ++i) pls.p[i] = (const float*)d_in[1 + i];
    const float* v1 = (const float*)d_in[10];
    const float* g1 = (const float*)d_in[11];
    const float* b1 = (const float*)d_in[12];
    const float* v2 = (const float*)d_in[13];
    const float* g2 = (const float*)d_in[14];
    const float* b2 = (const float*)d_in[15];
    const float* vl = (const float*)d_in[16];
    const float* gl = (const float*)d_in[17];
    const float* bl = (const float*)d_in[18];

    short* ws16 = (short*)d_ws;
    short* W1h = ws16;                    // 256*576
    short* W1l = ws16 + 147456;
    short* W2h = ws16 + 294912;           // 256*256
    short* W2l = ws16 + 360448;
    short* Wlh = ws16 + 425984;           // 128*256 (padded)
    short* Wll = ws16 + 458752;
    float* tpl = (float*)(ws16 + 491520); // transposed planes: 16515072 floats
    const size_t need_t = (size_t)491520 * 2 + (size_t)16515072 * 4;
    const int use_t = (ws_size >= need_t) ? 1 : 0;

    prep_weights<<<640, 64, 0, stream>>>(v1, g1, v2, g2, vl, gl,
                                         W1h, W1l, W2h, W2l, Wlh, Wll);
    if (use_t) transpose_planes<<<4032, 256, 0, stream>>>(pls, tpl);
    fused_kernel<<<NPTS / 128, 256, 0, stream>>>(x, pls, tpl, use_t,
                                                 W1h, W1l, W2h, W2l, Wlh, Wll,
                                                 b1, b2, bl, (float*)d_out);
}

// Round 3
// 919.997 us; speedup vs baseline: 1.5809x; 1.0042x over previous
//
#include <hip/hip_runtime.h>
#include <math.h>

#define NPTS 131072

typedef short s16x8 __attribute__((ext_vector_type(8)));
typedef short s16x4 __attribute__((ext_vector_type(4)));
typedef float f32x4 __attribute__((ext_vector_type(4)));

struct Planes9 { const float* p[9]; };

__device__ __forceinline__ float sp100(float h) {
    float z = 100.0f * h;
    return (fmaxf(z, 0.0f) + log1pf(__expf(-fabsf(z)))) * 0.01f;
}

__device__ __forceinline__ short f2bf(float f) {
    union { float f; unsigned u; } a; a.f = f;
    unsigned u = a.u;
    return (short)((u + 0x7FFFu + ((u >> 16) & 1u)) >> 16);
}
__device__ __forceinline__ float bf2f(short h) {
    union { unsigned u; float f; } a; a.u = ((unsigned)(unsigned short)h) << 16;
    return a.f;
}

__device__ __forceinline__ f32x4 mm(s16x8 a, s16x8 b, f32x4 c) {
    return __builtin_amdgcn_mfma_f32_16x16x32_bf16(a, b, c, 0, 0, 0);
}

// ======================= gather kernel: 4 threads/point, 16 ch each ====================
// Writes feat bf16 hi/lo, plane-major: [9][NPTS][64] shorts.
__global__ __launch_bounds__(256) void gather_kernel(
    const float* __restrict__ x, const float* __restrict__ tpl,
    short* __restrict__ fH, short* __restrict__ fL)
{
    const int tid = blockIdx.x * 256 + threadIdx.x;
    const int pt = tid >> 2, q = tid & 3;
    const float xc0 = x[pt*3+0], xc1 = x[pt*3+1], xc2 = x[pt*3+2];
    #pragma unroll 1
    for (int pl = 0; pl < 9; ++pl) {
        const int grp = (pl >= 6) ? 2 : (pl >= 3 ? 1 : 0);
        const int r = pl - grp * 3;
        const int L = 64 << r;
        const float u = (grp == 2) ? xc1 : xc0;
        const float v = (grp == 0) ? xc1 : xc2;
        float ix = (u + 1.0f) * 0.5f * (float)(L - 1);
        float iy = (v + 1.0f) * 0.5f * (float)(L - 1);
        float ix0 = floorf(ix), iy0 = floorf(iy);
        float wx = ix - ix0, wy = iy - iy0;
        int x0 = (int)fminf(fmaxf(ix0, 0.f), (float)(L-1));
        int x1 = (int)fminf(fmaxf(ix0+1.f, 0.f), (float)(L-1));
        int y0 = (int)fminf(fmaxf(iy0, 0.f), (float)(L-1));
        int y1 = (int)fminf(fmaxf(iy0+1.f, 0.f), (float)(L-1));
        float wnw = (1.f-wx)*(1.f-wy), wne = wx*(1.f-wy), wsw = (1.f-wx)*wy, wse = wx*wy;

        size_t poff = (size_t)grp * 5505024 + (r == 0 ? 0u : (r == 1 ? 262144u : 1310720u));
        const float* P = tpl + poff;
        const float4* c00 = (const float4*)(P + ((size_t)(y0*L + x0)*64 + q*16));
        const float4* c01 = (const float4*)(P + ((size_t)(y0*L + x1)*64 + q*16));
        const float4* c10 = (const float4*)(P + ((size_t)(y1*L + x0)*64 + q*16));
        const float4* c11 = (const float4*)(P + ((size_t)(y1*L + x1)*64 + q*16));
        float f[16];
        #pragma unroll
        for (int qq = 0; qq < 4; ++qq) {
            float4 a = c00[qq], b = c01[qq], c = c10[qq], d = c11[qq];
            f[qq*4+0] = wnw*a.x + wne*b.x + wsw*c.x + wse*d.x;
            f[qq*4+1] = wnw*a.y + wne*b.y + wsw*c.y + wse*d.y;
            f[qq*4+2] = wnw*a.z + wne*b.z + wsw*c.z + wse*d.z;
            f[qq*4+3] = wnw*a.w + wne*b.w + wsw*c.w + wse*d.w;
        }
        s16x8 hi8[2], lo8[2];
        #pragma unroll
        for (int e = 0; e < 16; ++e) {
            float vv = f[e];
            short hb = f2bf(vv);
            hi8[e >> 3][e & 7] = hb;
            lo8[e >> 3][e & 7] = f2bf(vv - bf2f(hb));
        }
        size_t o = (size_t)pl * 8388608 + (size_t)pt * 64 + q * 16;
        *(s16x8*)(fH + o)     = hi8[0];
        *(s16x8*)(fH + o + 8) = hi8[1];
        *(s16x8*)(fL + o)     = lo8[0];
        *(s16x8*)(fL + o + 8) = lo8[1];
    }
}

// ======================= MLP kernel: 128 points / block, 4 waves =======================
// L1 B-operand straight from global feat (no LDS, no barriers); L2/L3 as validated in R2.
__global__ __launch_bounds__(256, 2) void mlp_kernel(
    const short* __restrict__ fH, const short* __restrict__ fL,
    const short* __restrict__ W1h, const short* __restrict__ W1l,
    const short* __restrict__ W2h, const short* __restrict__ W2l,
    const short* __restrict__ Wlh, const short* __restrict__ Wll,
    const float* __restrict__ b1, const float* __restrict__ b2, const float* __restrict__ bl,
    float* __restrict__ out)
{
    __shared__ __align__(16) char smem[65536];   // hB [128 pt][256 k] bf16, swizzled
    const int t = threadIdx.x, blk = blockIdx.x;
    const int w = t >> 6, ln = t & 63, s = ln & 15, g = ln >> 4;
    const int swz = (s & 7) << 4;

    f32x4 acc[8][4];
    const f32x4 fz = {0.f, 0.f, 0.f, 0.f};
    #pragma unroll
    for (int mt = 0; mt < 8; ++mt)
        #pragma unroll
        for (int j = 0; j < 4; ++j) acc[mt][j] = fz;

    const size_t ptbase = (size_t)blk * 128;

    // ---------------- Layer 1: K = 576 (18 steps of 32), 3-term split ----------------
    #pragma unroll 2
    for (int ks = 0; ks < 18; ++ks) {
        const int pl = ks >> 1;
        const int kin = (ks & 1) * 32 + g * 8;
        const short* bH = fH + (size_t)pl * 8388608 + (ptbase + s) * 64 + kin;
        const short* bL = fL + (size_t)pl * 8388608 + (ptbase + s) * 64 + kin;
        s16x8 Ah[4], Al[4];
        #pragma unroll
        for (int j = 0; j < 4; ++j) {
            size_t ro = (size_t)((4*j + w)*16 + s) * 576 + (size_t)(ks*32 + g*8);
            Ah[j] = *(const s16x8*)(W1h + ro);
            Al[j] = *(const s16x8*)(W1l + ro);
        }
        #pragma unroll
        for (int mt = 0; mt < 8; ++mt) {
            s16x8 Bh = *(const s16x8*)(bH + mt * 1024);
            s16x8 Bl = *(const s16x8*)(bL + mt * 1024);
            #pragma unroll
            for (int j = 0; j < 4; ++j) {
                acc[mt][j] = mm(Ah[j], Bh, acc[mt][j]);
                acc[mt][j] = mm(Ah[j], Bl, acc[mt][j]);
                acc[mt][j] = mm(Al[j], Bh, acc[mt][j]);
            }
        }
    }

    // ======== bias + softplus, stage h1 (bf16) to hB [128 m][256 k] ========
    #pragma unroll
    for (int j = 0; j < 4; ++j) {
        f32x4 bv = *(const f32x4*)(b1 + (4*j + w)*16 + g*4);
        #pragma unroll
        for (int mt = 0; mt < 8; ++mt) {
            f32x4 a = acc[mt][j];
            s16x4 hq;
            hq[0] = f2bf(sp100(a[0] + bv[0]));
            hq[1] = f2bf(sp100(a[1] + bv[1]));
            hq[2] = f2bf(sp100(a[2] + bv[2]));
            hq[3] = f2bf(sp100(a[3] + bv[3]));
            int off = (mt*16 + s)*512 + ((((4*j + w)*32) + g*8) ^ swz);
            *(s16x4*)(smem + off) = hq;
        }
    }
    #pragma unroll
    for (int mt = 0; mt < 8; ++mt)
        #pragma unroll
        for (int j = 0; j < 4; ++j) acc[mt][j] = fz;
    __syncthreads();

    // ---------------- Layer 2: K = 256, split weights (2-term) ----------------
    #pragma unroll 1
    for (int ks = 0; ks < 8; ++ks) {
        s16x8 Ah[4], Al[4];
        #pragma unroll
        for (int j = 0; j < 4; ++j) {
            size_t ro = (size_t)((4*j + w)*16 + s) * 256 + (size_t)(ks*32 + g*8);
            Ah[j] = *(const s16x8*)(W2h + ro);
            Al[j] = *(const s16x8*)(W2l + ro);
        }
        #pragma unroll
        for (int mt = 0; mt < 8; ++mt) {
            int off = (mt*16 + s)*512 + ((ks*64 + g*16) ^ swz);
            s16x8 B = *(s16x8*)(smem + off);
            #pragma unroll
            for (int j = 0; j < 4; ++j) {
                acc[mt][j] = mm(Ah[j], B, acc[mt][j]);
                acc[mt][j] = mm(Al[j], B, acc[mt][j]);
            }
        }
    }
    __syncthreads();   // all hB reads done before overwrite with h2

    // ======== bias + softplus, stage h2 ========
    #pragma unroll
    for (int j = 0; j < 4; ++j) {
        f32x4 bv = *(const f32x4*)(b2 + (4*j + w)*16 + g*4);
        #pragma unroll
        for (int mt = 0; mt < 8; ++mt) {
            f32x4 a = acc[mt][j];
            s16x4 hq;
            hq[0] = f2bf(sp100(a[0] + bv[0]));
            hq[1] = f2bf(sp100(a[1] + bv[1]));
            hq[2] = f2bf(sp100(a[2] + bv[2]));
            hq[3] = f2bf(sp100(a[3] + bv[3]));
            int off = (mt*16 + s)*512 + ((((4*j + w)*32) + g*8) ^ swz);
            *(s16x4*)(smem + off) = hq;
        }
    }
    __syncthreads();

    // ---------------- Layer 3: Wl padded to 128 rows; wave w does tiles w, 4+w --------
    f32x4 acc3[8][2];
    #pragma unroll
    for (int mt = 0; mt < 8; ++mt) { acc3[mt][0] = fz; acc3[mt][1] = fz; }
    #pragma unroll 1
    for (int ks = 0; ks < 8; ++ks) {
        s16x8 Ah[2], Al[2];
        #pragma unroll
        for (int j = 0; j < 2; ++j) {
            size_t ro = (size_t)((4*j + w)*16 + s) * 256 + (size_t)(ks*32 + g*8);
            Ah[j] = *(const s16x8*)(Wlh + ro);
            Al[j] = *(const s16x8*)(Wll + ro);
        }
        #pragma unroll
        for (int mt = 0; mt < 8; ++mt) {
            int off = (mt*16 + s)*512 + ((ks*64 + g*16) ^ swz);
            s16x8 B = *(s16x8*)(smem + off);
            #pragma unroll
            for (int j = 0; j < 2; ++j) {
                acc3[mt][j] = mm(Ah[j], B, acc3[mt][j]);
                acc3[mt][j] = mm(Al[j], B, acc3[mt][j]);
            }
        }
    }

    // ---------------- output: feat (P,64) + dsdf (P,1) ----------------
    {
        f32x4 bv = *(const f32x4*)(bl + w*16 + g*4);
        #pragma unroll
        for (int mt = 0; mt < 8; ++mt) {
            size_t p = (size_t)blk*128 + (size_t)(mt*16 + s);
            f32x4 o = acc3[mt][0];
            o[0] += bv[0]; o[1] += bv[1]; o[2] += bv[2]; o[3] += bv[3];
            *(f32x4*)(out + p*64 + (size_t)(w*16 + g*4)) = o;
            if (w == 0 && g == 0)
                out[(size_t)NPTS*64 + p] = acc3[mt][1][0] + bl[64];
        }
    }
}

// ================= fallback fused kernel (validated R2 path) ==============
__global__ __launch_bounds__(256, 2) void fused_kernel(
    const float* __restrict__ x, Planes9 pls, const float* __restrict__ tpl, int use_t,
    const short* __restrict__ W1h, const short* __restrict__ W1l,
    const short* __restrict__ W2h, const short* __restrict__ W2l,
    const short* __restrict__ Wlh, const short* __restrict__ Wll,
    const float* __restrict__ b1, const float* __restrict__ b2, const float* __restrict__ bl,
    float* __restrict__ out)
{
    __shared__ __align__(16) char smem[65536];
    __shared__ float xs[384];
    const int t = threadIdx.x, blk = blockIdx.x;
    for (int i = t; i < 384; i += 256) xs[i] = x[(size_t)blk * 384 + i];

    const int w = t >> 6, ln = t & 63, s = ln & 15, g = ln >> 4;
    const int swz = (s & 7) << 4;
    const int pt = t & 127, kh = t >> 7;
    const int ptswz = (pt & 7) << 4;

    f32x4 acc[8][4];
    const f32x4 fz = {0.f, 0.f, 0.f, 0.f};
    #pragma unroll
    for (int mt = 0; mt < 8; ++mt)
        #pragma unroll
        for (int j = 0; j < 4; ++j) acc[mt][j] = fz;

    __syncthreads();

    #pragma unroll 1
    for (int pl = 0; pl < 9; ++pl) {
        const int grp = (pl >= 6) ? 2 : (pl >= 3 ? 1 : 0);
        const int r = pl - grp * 3;
        const int L = 64 << r;
        float u, v;
        { float xc0 = xs[pt*3+0], xc1 = xs[pt*3+1], xc2 = xs[pt*3+2];
          u = (grp == 2) ? xc1 : xc0;
          v = (grp == 0) ? xc1 : xc2; }
        float ix = (u + 1.0f) * 0.5f * (float)(L - 1);
        float iy = (v + 1.0f) * 0.5f * (float)(L - 1);
        float ix0 = floorf(ix), iy0 = floorf(iy);
        float wx = ix - ix0, wy = iy - iy0;
        int x0 = (int)fminf(fmaxf(ix0, 0.f), (float)(L-1));
        int x1 = (int)fminf(fmaxf(ix0+1.f, 0.f), (float)(L-1));
        int y0 = (int)fminf(fmaxf(iy0, 0.f), (float)(L-1));
        int y1 = (int)fminf(fmaxf(iy0+1.f, 0.f), (float)(L-1));
        float wnw = (1.f-wx)*(1.f-wy), wne = wx*(1.f-wy), wsw = (1.f-wx)*wy, wse = wx*wy;

        float f[32];
        if (use_t) {
            size_t poff = (size_t)grp * 5505024 + (r == 0 ? 0u : (r == 1 ? 262144u : 1310720u));
            const float* P = tpl + poff;
            const float4* c00 = (const float4*)(P + ((size_t)(y0*L + x0)*64 + kh*32));
            const float4* c01 = (const float4*)(P + ((size_t)(y0*L + x1)*64 + kh*32));
            const float4* c10 = (const float4*)(P + ((size_t)(y1*L + x0)*64 + kh*32));
            const float4* c11 = (const float4*)(P + ((size_t)(y1*L + x1)*64 + kh*32));
            #pragma unroll
            for (int qq = 0; qq < 8; ++qq) {
                float4 a = c00[qq], b = c01[qq], c = c10[qq], d = c11[qq];
                f[qq*4+0] = wnw*a.x + wne*b.x + wsw*c.x + wse*d.x;
                f[qq*4+1] = wnw*a.y + wne*b.y + wsw*c.y + wse*d.y;
                f[qq*4+2] = wnw*a.z + wne*b.z + wsw*c.z + wse*d.z;
                f[qq*4+3] = wnw*a.w + wne*b.w + wsw*c.w + wse*d.w;
            }
        } else {
            const float* P = pls.p[pl];
            const int i00 = y0*L+x0, i01 = y0*L+x1, i10 = y1*L+x0, i11 = y1*L+x1;
            #pragma unroll 8
            for (int c = 0; c < 32; ++c) {
                const float* pc = P + (size_t)(kh*32 + c) * L * L;
                f[c] = wnw*pc[i00] + wne*pc[i01] + wsw*pc[i10] + wse*pc[i11];
            }
        }
        #pragma unroll
        for (int qq = 0; qq < 4; ++qq) {
            s16x8 hi8, lo8;
            #pragma unroll
            for (int e = 0; e < 8; ++e) {
                float vv = f[qq*8+e];
                short hb = f2bf(vv);
                hi8[e] = hb;
                lo8[e] = f2bf(vv - bf2f(hb));
            }
            int off = pt*128 + ((kh*64 + qq*16) ^ ptswz);
            *(s16x8*)(smem + off)         = hi8;
            *(s16x8*)(smem + 16384 + off) = lo8;
        }
        __syncthreads();

        #pragma unroll
        for (int ks = 0; ks < 2; ++ks) {
            s16x8 Ah[4], Al[4];
            #pragma unroll
            for (int j = 0; j < 4; ++j) {
                size_t ro = (size_t)((4*j + w)*16 + s) * 576 + (size_t)(pl*64 + ks*32 + g*8);
                Ah[j] = *(const s16x8*)(W1h + ro);
                Al[j] = *(const s16x8*)(W1l + ro);
            }
            #pragma unroll
            for (int mt = 0; mt < 8; ++mt) {
                int off = (mt*16 + s)*128 + ((ks*64 + g*16) ^ swz);
                s16x8 Bh = *(s16x8*)(smem + off);
                s16x8 Bl = *(s16x8*)(smem + 16384 + off);
                #pragma unroll
                for (int j = 0; j < 4; ++j) {
                    acc[mt][j] = mm(Ah[j], Bh, acc[mt][j]);
                    acc[mt][j] = mm(Ah[j], Bl, acc[mt][j]);
                    acc[mt][j] = mm(Al[j], Bh, acc[mt][j]);
                }
            }
        }
        __syncthreads();
    }

    #pragma unroll
    for (int j = 0; j < 4; ++j) {
        f32x4 bv = *(const f32x4*)(b1 + (4*j + w)*16 + g*4);
        #pragma unroll
        for (int mt = 0; mt < 8; ++mt) {
            f32x4 a = acc[mt][j];
            s16x4 hq;
            hq[0] = f2bf(sp100(a[0] + bv[0]));
            hq[1] = f2bf(sp100(a[1] + bv[1]));
            hq[2] = f2bf(sp100(a[2] + bv[2]));
            hq[3] = f2bf(sp100(a[3] + bv[3]));
            int off = (mt*16 + s)*512 + ((((4*j + w)*32) + g*8) ^ swz);
            *(s16x4*)(smem + off) = hq;
        }
    }
    #pragma unroll
    for (int mt = 0; mt < 8; ++mt)
        #pragma unroll
        for (int j = 0; j < 4; ++j) acc[mt][j] = fz;
    __syncthreads();

    #pragma unroll 1
    for (int ks = 0; ks < 8; ++ks) {
        s16x8 Ah[4], Al[4];
        #pragma unroll
        for (int j = 0; j < 4; ++j) {
            size_t ro = (size_t)((4*j + w)*16 + s) * 256 + (size_t)(ks*32 + g*8);
            Ah[j] = *(const s16x8*)(W2h + ro);
            Al[j] = *(const s16x8*)(W2l + ro);
        }
        #pragma unroll
        for (int mt = 0; mt < 8; ++mt) {
            int off = (mt*16 + s)*512 + ((ks*64 + g*16) ^ swz);
            s16x8 B = *(s16x8*)(smem + off);
            #pragma unroll
            for (int j = 0; j < 4; ++j) {
                acc[mt][j] = mm(Ah[j], B, acc[mt][j]);
                acc[mt][j] = mm(Al[j], B, acc[mt][j]);
            }
        }
    }
    __syncthreads();

    #pragma unroll
    for (int j = 0; j < 4; ++j) {
        f32x4 bv = *(const f32x4*)(b2 + (4*j + w)*16 + g*4);
        #pragma unroll
        for (int mt = 0; mt < 8; ++mt) {
            f32x4 a = acc[mt][j];
            s16x4 hq;
            hq[0] = f2bf(sp100(a[0] + bv[0]));
            hq[1] = f2bf(sp100(a[1] + bv[1]));
            hq[2] = f2bf(sp100(a[2] + bv[2]));
            hq[3] = f2bf(sp100(a[3] + bv[3]));
            int off = (mt*16 + s)*512 + ((((4*j + w)*32) + g*8) ^ swz);
            *(s16x4*)(smem + off) = hq;
        }
    }
    __syncthreads();

    f32x4 acc3[8][2];
    #pragma unroll
    for (int mt = 0; mt < 8; ++mt) { acc3[mt][0] = fz; acc3[mt][1] = fz; }
    #pragma unroll 1
    for (int ks = 0; ks < 8; ++ks) {
        s16x8 Ah[2], Al[2];
        #pragma unroll
        for (int j = 0; j < 2; ++j) {
            size_t ro = (size_t)((4*j + w)*16 + s) * 256 + (size_t)(ks*32 + g*8);
            Ah[j] = *(const s16x8*)(Wlh + ro);
            Al[j] = *(const s16x8*)(Wll + ro);
        }
        #pragma unroll
        for (int mt = 0; mt < 8; ++mt) {
            int off = (mt*16 + s)*512 + ((ks*64 + g*16) ^ swz);
            s16x8 B = *(s16x8*)(smem + off);
            #pragma unroll
            for (int j = 0; j < 2; ++j) {
                acc3[mt][j] = mm(Ah[j], B, acc3[mt][j]);
                acc3[mt][j] = mm(Al[j], B, acc3[mt][j]);
            }
        }
    }

    {
        f32x4 bv = *(const f32x4*)(bl + w*16 + g*4);
        #pragma unroll
        for (int mt = 0; mt < 8; ++mt) {
            size_t p = (size_t)blk*128 + (size_t)(mt*16 + s);
            f32x4 o = acc3[mt][0];
            o[0] += bv[0]; o[1] += bv[1]; o[2] += bv[2]; o[3] += bv[3];
            *(f32x4*)(out + p*64 + (size_t)(w*16 + g*4)) = o;
            if (w == 0 && g == 0)
                out[(size_t)NPTS*64 + p] = acc3[mt][1][0] + bl[64];
        }
    }
}

// ---------------- weight-norm + bf16 hi/lo split (row-major n x k) -------
__global__ __launch_bounds__(64) void prep_weights(
    const float* __restrict__ v1, const float* __restrict__ g1,
    const float* __restrict__ v2, const float* __restrict__ g2,
    const float* __restrict__ vl, const float* __restrict__ gl,
    short* __restrict__ W1h, short* __restrict__ W1l,
    short* __restrict__ W2h, short* __restrict__ W2l,
    short* __restrict__ Wlh, short* __restrict__ Wll)
{
    int i = blockIdx.x, t = threadIdx.x;
    const float* src; float gv; int K; short *dh, *dl; size_t ro;
    if (i < 256)      { src = v1 + (size_t)i*576; gv = g1[i]; K = 576; dh = W1h; dl = W1l; ro = (size_t)i*576; }
    else if (i < 512) { int rr = i-256; src = v2 + (size_t)rr*256; gv = g2[rr]; K = 256; dh = W2h; dl = W2l; ro = (size_t)rr*256; }
    else {
        int rr = i-512;
        K = 256; dh = Wlh; dl = Wll; ro = (size_t)rr*256;
        if (rr >= 65) {
            for (int k = t; k < 256; k += 64) { dh[ro+k] = 0; dl[ro+k] = 0; }
            return;
        }
        src = vl + (size_t)rr*256; gv = gl[rr];
    }
    float ssum = 0.f;
    for (int k = t; k < K; k += 64) { float wv = src[k]; ssum += wv*wv; }
    #pragma unroll
    for (int off = 32; off > 0; off >>= 1) ssum += __shfl_xor(ssum, off, 64);
    float sc = gv / sqrtf(ssum);
    for (int k = t; k < K; k += 64) {
        float wv = src[k] * sc;
        short hb = f2bf(wv);
        dh[ro + k] = hb;
        dl[ro + k] = f2bf(wv - bf2f(hb));
    }
}

// ---------------- planes (C,H,W) -> (H,W,C) fp32 ----------------
__global__ __launch_bounds__(256) void transpose_planes(Planes9 pls, float* __restrict__ dst)
{
    __shared__ float tile[64 * 65];
    int b = blockIdx.x;
    int g = b / 1344, rem = b % 1344;
    int r, t2;
    if (rem < 64)       { r = 0; t2 = rem; }
    else if (rem < 320) { r = 1; t2 = rem - 64; }
    else                { r = 2; t2 = rem - 320; }
    int L = 64 << r;
    int wt = L >> 6;
    int y = t2 / wt, xt = t2 % wt;
    const float* sp = pls.p[g * 3 + r];
    float* dp = dst + (size_t)g * 5505024 + (r == 0 ? 0 : (r == 1 ? 262144 : 1310720));
    int t = threadIdx.x;
    int rowbase = y * L + xt * 64;
    {
        int xi = t & 63, cq = t >> 6;
        #pragma unroll
        for (int cc = 0; cc < 16; ++cc) {
            int c = cq * 16 + cc;
            tile[c * 65 + xi] = sp[(size_t)c * L * L + rowbase + xi];
        }
    }
    __syncthreads();
    {
        int ci = t & 63, xq = t >> 6;
        #pragma unroll
        for (int xx = 0; xx < 16; ++xx) {
            int xcol = xq * 16 + xx;
            dp[(size_t)(rowbase + xcol) * 64 + ci] = tile[ci * 65 + xcol];
        }
    }
}

extern "C" void kernel_launch(void* const* d_in, const int* in_sizes, int n_in,
                              void* d_out, int out_size, void* d_ws, size_t ws_size,
                              hipStream_t stream)
{
    const float* x = (const float*)d_in[0];
    Planes9 pls;
    for (int i = 0; i < 9; ++i) pls.p[i] = (const float*)d_in[1 + i];
    const float* v1 = (const float*)d_in[10];
    const float* g1 = (const float*)d_in[11];
    const float* b1 = (const float*)d_in[12];
    const float* v2 = (const float*)d_in[13];
    const float* g2 = (const float*)d_in[14];
    const float* b2 = (const float*)d_in[15];
    const float* vl = (const float*)d_in[16];
    const float* gl = (const float*)d_in[17];
    const float* bl = (const float*)d_in[18];

    short* ws16 = (short*)d_ws;
    short* W1h = ws16;                    // 256*576
    short* W1l = ws16 + 147456;
    short* W2h = ws16 + 294912;           // 256*256
    short* W2l = ws16 + 360448;
    short* Wlh = ws16 + 425984;           // 128*256 (padded)
    short* Wll = ws16 + 458752;
    float* tpl = (float*)(ws16 + 491520); // transposed planes: 16515072 floats
    const size_t need_t = (size_t)491520 * 2 + (size_t)16515072 * 4;   // 67,043,328 B
    short* fH = (short*)((char*)d_ws + need_t);      // 9*131072*64 shorts
    short* fL = fH + 75497472;
    const size_t need_split = need_t + (size_t)2 * 150994944;          // 369,033,216 B

    prep_weights<<<640, 64, 0, stream>>>(v1, g1, v2, g2, vl, gl,
                                         W1h, W1l, W2h, W2l, Wlh, Wll);
    if (ws_size >= need_split) {
        transpose_planes<<<4032, 256, 0, stream>>>(pls, tpl);
        gather_kernel<<<2048, 256, 0, stream>>>(x, tpl, fH, fL);
        mlp_kernel<<<NPTS / 128, 256, 0, stream>>>(fH, fL,
                                                   W1h, W1l, W2h, W2l, Wlh, Wll,
                                                   b1, b2, bl, (float*)d_out);
    } else {
        const int use_t = (ws_size >= need_t) ? 1 : 0;
        if (use_t) transpose_planes<<<4032, 256, 0, stream>>>(pls, tpl);
        fused_kernel<<<NPTS / 128, 256, 0, stream>>>(x, pls, tpl, use_t,
                                                     W1h, W1l, W2h, W2l, Wlh, Wll,
                                                     b1, b2, bl, (float*)d_out);
    }
}